// Round 8
// baseline (2978.465 us; speedup 1.0000x reference)
//
#include <hip/hip_runtime.h>
#include <hip/hip_fp16.h>
#include <cstdio>

// EmbeddingCellLSTM: B=32, S=2048, IN=64, EMB=32, H=256, 4H=1024
//  k1 pack_kernel : W_hh fp32 -> i8 (scale 2032) 16B K-fragments (lane&15 -> W row, lane>>4 -> K-chunk).
//  k2 zx_kernel   : zx = (concat(x,emb) @ W_ih^T + b) fp16; block = 64-row stripe, stages x once.
//  k3 lstm_kernel : r8 = TWO BATCHES PER CU. 16 blocks; block bi owns batches bi and bi+16.
//                   Weights (64 regs) shared by both batches. Per wave per step:
//                   MFMA(X)->tail(X)->MFMA(Y)->tail(Y)->barrier, X/Y batch order flipped by
//                   wave parity so half the waves' MFMA clusters cover the other half's tails.
//                   Rationale: matrix floor is 1024 cyc/batch-step (measured r4-r7, 64
//                   MFMA-inst/SIMD x 16 cyc); the ~670cyc/step exposed tail (r7) is the
//                   last wave's dependent latency at the barrier -> amortize it over 2
//                   batch-steps: step-pair ~= 2048 + ~400 -> ~1250 cyc/batch-step.
//                   Core math per batch unchanged (transposed MFMA, distributed activations,
//                   wave-wide bpermute gather, q==0 writes) -> absmax identical.

#define WPK_OFF (134217728u)   // zx = 32*2048*1024*2 bytes, then wpk 256 KB

typedef int v4i __attribute__((ext_vector_type(4)));

static __device__ __forceinline__ unsigned short f16bits(float v) {
  _Float16 h = (_Float16)v;
  return __builtin_bit_cast(unsigned short, h);
}

static __device__ __forceinline__ float h2f(unsigned short b) {
  return (float)__builtin_bit_cast(_Float16, b);
}

// ---------------- k1: pack W_hh -> i8 MFMA K-fragments ----------------
// tile = g*4+c ; thread t -> w=t>>6, lane: m=lane&15 (row), q=lane>>4
// frag byte j = W[g*256 + 16w + m][c*64 + q*16 + j] ; wq = rint(w*2032), |w|<1/16 -> |wq|<=127
__global__ __launch_bounds__(1024) void pack_kernel(const float* __restrict__ Whh,
                                                    uint4* __restrict__ wpk) {
  int tile = blockIdx.x;            // 0..15
  int g = tile >> 2, c = tile & 3;
  int t = threadIdx.x;
  int w = t >> 6, lane = t & 63, m = lane & 15, q = lane >> 4;
  int row = g * 256 + w * 16 + m;
  const float* src = Whh + row * 256 + c * 64 + q * 16;
  unsigned int pk[4];
#pragma unroll
  for (int d = 0; d < 4; d++) {
    unsigned int v = 0;
#pragma unroll
    for (int e = 0; e < 4; e++) {
      int qv = (int)rintf(src[d * 4 + e] * 2032.0f);
      v |= ((unsigned int)(qv & 255)) << (8 * e);
    }
    pk[d] = v;
  }
  uint4 o; o.x = pk[0]; o.y = pk[1]; o.z = pk[2]; o.w = pk[3];
  wpk[tile * 1024 + t] = o;
}

// ---------------- k2: zx = concat(x,emb) @ W_ih^T + b (fp16, natural row order) ----------------
// One block per 64-row stripe; x/emb staged once, 16 column tiles looped in-block.
__global__ __launch_bounds__(256) void zx_kernel(const float* __restrict__ x,
                                                 const float* __restrict__ emb,
                                                 const float* __restrict__ Wih,
                                                 const float* __restrict__ bias,
                                                 unsigned short* __restrict__ zx) {
  __shared__ __align__(16) float XeT[96][68];
  __shared__ __align__(16) float WT[96][68];
  int mt = blockIdx.x;              // 0..1023
  int m0 = mt * 64;
  int tid = threadIdx.x;
  for (int idx = tid; idx < 6144; idx += 256) {
    int r = idx / 96, k = idx - r * 96;
    size_t m = (size_t)(m0 + r);
    float v = (k < 64) ? x[m * 64 + k] : emb[m * 32 + (k - 64)];
    XeT[k][r] = v;
  }
  int ty = tid >> 4, tx = tid & 15;
  int r0 = ty * 4, c0 = tx * 4;
  for (int nt = 0; nt < 16; nt++) {
    int n0 = nt * 64;
    __syncthreads();                // protect WT vs previous iter's readers (covers XeT stage on iter 0)
    for (int idx = tid; idx < 6144; idx += 256) {
      int c = idx / 96, k = idx - c * 96;
      WT[k][c] = Wih[(size_t)(n0 + c) * 96 + k];
    }
    __syncthreads();
    float acc[4][4] = {};
    for (int k = 0; k < 96; k++) {
      float4 a = *(const float4*)&XeT[k][r0];
      float4 wv4 = *(const float4*)&WT[k][c0];
      float av[4] = {a.x, a.y, a.z, a.w};
      float wv[4] = {wv4.x, wv4.y, wv4.z, wv4.w};
#pragma unroll
      for (int i = 0; i < 4; i++)
#pragma unroll
        for (int jj = 0; jj < 4; jj++) acc[i][jj] += av[i] * wv[jj];
    }
#pragma unroll
    for (int i = 0; i < 4; i++) {
      size_t m = (size_t)(m0 + r0 + i);
#pragma unroll
      for (int jj = 0; jj < 4; jj++) {
        int col = n0 + c0 + jj;
        zx[m * 1024 + (size_t)col] = f16bits(acc[i][jj] + bias[col]);
      }
    }
  }
}

// ---------------- k3: persistent LSTM, 2 batches/CU (transposed i8 MFMA) ----------------
__global__ __launch_bounds__(1024, 4) void lstm_kernel(const unsigned short* __restrict__ zx,
                                                       const v4i* __restrict__ wpk,
                                                       float* __restrict__ out) {
  __shared__ __align__(16) char hq[2][2][256];   // [batch-slot][buf][unit]
  const int t = threadIdx.x, bi = blockIdx.x;    // bi in 0..15
  const int w = t >> 6, lane = t & 63, q = lane >> 4, n = lane & 15;

  // full W_hh residency: 16 frags x 16B i8 = 64 regs, SHARED by both batches
  v4i wf[16];
#pragma unroll
  for (int i = 0; i < 16; i++) wf[i] = wpk[i * 1024 + t];

  if (t < 256) ((unsigned int*)hq)[t] = 0;       // zero all 4 h buffers (2 slots x 2 bufs x 256 i8)
  __syncthreads();

  // static stagger prio for MFMA clusters (robust to either wave->SIMD map)
  const int pr = 3 - (((w >> 2) ^ w) & 3);

  const float dq = 1.0f / (2032.0f * 127.0f);
  const int u = w * 16 + n;                      // this lane's unit
  const bool isg = (q == 2);                     // lane's gate = q ; gate 2 is tanh
  const float sc = isg ? 2.88539008f : 1.44269504f;
  const bool wr = (q == 0);
  const int bpb = n << 2;                        // bpermute byte base: lanes (g*16+n), g=0..3
  const v4i zerov = {0, 0, 0, 0};                // persistent MFMA C operand (D != C)

  // wave-parity batch order: even waves do (bi) first, odd waves (bi+16) first
  const int bX = (w & 1) ? (bi + 16) : bi;
  const int bY = (w & 1) ? bi : (bi + 16);
  const int slX = (w & 1), slY = slX ^ 1;        // LDS slot = batch index bit4
  const unsigned short* zpX = zx + (size_t)bX * (2048u * 1024u) + (unsigned)(q * 256 + u);
  const unsigned short* zpY = zx + (size_t)bY * (2048u * 1024u) + (unsigned)(q * 256 + u);
  float* opX = out + (size_t)bX * (2048u * 256u) + u;
  float* opY = out + (size_t)bY * (2048u * 256u) + u;

  float cstX = 0.f, hlX = 0.f, cstY = 0.f, hlY = 0.f;
  unsigned short zaX = zpX[0], zbX = zpX[1024];
  unsigned short zaY = zpY[0], zbY = zpY[1024];

// One batch-phase: read h, 16 MFMAs, one activation/lane, bpermute gather, c/h update, write.
// ZREG distance-2 reload; s>=2048 prefetch lands in allocated wpk region (bounds-checked).
#define PHASE(SL, BUF, NBUF, ZREG, ZP, CST, HL, OP, SIDX)                             \
  {                                                                                   \
    const char* hc = &hq[SL][BUF][0];                                                 \
    v4i bq[4];                                                                        \
    _Pragma("unroll")                                                                 \
    for (int c = 0; c < 4; c++) bq[c] = *(const v4i*)(hc + c * 64 + q * 16);          \
    unsigned short zu = ZREG;                                                         \
    ZREG = (ZP)[(size_t)((SIDX) + 2) << 10];                                          \
    if (pr == 3) __builtin_amdgcn_s_setprio(3);                                       \
    else if (pr == 2) __builtin_amdgcn_s_setprio(2);                                  \
    else if (pr == 1) __builtin_amdgcn_s_setprio(1);                                  \
    v4i acc[4];                                                                       \
    _Pragma("unroll")                                                                 \
    for (int gg = 0; gg < 4; gg++)                                                    \
      acc[gg] = __builtin_amdgcn_mfma_i32_16x16x64_i8(bq[0], wf[gg * 4 + 0], zerov, 0, 0, 0); \
    _Pragma("unroll")                                                                 \
    for (int c = 1; c < 4; c++)                                                       \
      _Pragma("unroll")                                                               \
      for (int gg = 0; gg < 4; gg++)                                                  \
        acc[gg] = __builtin_amdgcn_mfma_i32_16x16x64_i8(bq[c], wf[gg * 4 + c], acc[gg], 0, 0, 0); \
    __builtin_amdgcn_s_setprio(0);                                                    \
    int tlo = (q & 1) ? acc[1][0] : acc[0][0];                                        \
    int thi = (q & 1) ? acc[3][0] : acc[2][0];                                        \
    int zi  = (q & 2) ? thi : tlo;                                                    \
    float z = (float)zi * dq + h2f(zu);                                               \
    float e = __builtin_amdgcn_exp2f(-sc * z);                                        \
    float r = __builtin_amdgcn_rcpf(1.f + e);                                         \
    float a = isg ? (2.f * r - 1.f) : r;                                              \
    int ab = __builtin_bit_cast(int, a);                                              \
    float ai = __builtin_bit_cast(float, __builtin_amdgcn_ds_bpermute(bpb + 0, ab));  \
    float af = __builtin_bit_cast(float, __builtin_amdgcn_ds_bpermute(bpb + 64, ab)); \
    float ag = __builtin_bit_cast(float, __builtin_amdgcn_ds_bpermute(bpb + 128, ab));\
    float ao = __builtin_bit_cast(float, __builtin_amdgcn_ds_bpermute(bpb + 192, ab));\
    float cn = af * (CST) + ai * ag;                                                  \
    float e2 = __builtin_amdgcn_exp2f(-2.88539008f * cn);                             \
    float th = 2.f * __builtin_amdgcn_rcpf(1.f + e2) - 1.f;                           \
    float h = ao * th;                                                                \
    (CST) = cn;                                                                       \
    (HL) = h;                                                                         \
    if (wr) {                                                                         \
      hq[SL][NBUF][u] = (char)(int)rintf(h * 127.0f);                                 \
      (OP)[(size_t)(SIDX) * 256] = h;                                                 \
    }                                                                                 \
  }

  for (int s = 0; s < 2048; s += 2) {
    PHASE(slX, 0, 1, zaX, zpX, cstX, hlX, opX, s)
    PHASE(slY, 0, 1, zaY, zpY, cstY, hlY, opY, s)
    __syncthreads();
    PHASE(slX, 1, 0, zbX, zpX, cstX, hlX, opX, s + 1)
    PHASE(slY, 1, 0, zbY, zpY, cstY, hlY, opY, s + 1)
    __syncthreads();
  }
#undef PHASE

  if (wr) {
    out[16777216u + (size_t)bX * 256 + u] = hlX;           // final h (batch X)
    out[16777216u + 8192u + (size_t)bX * 256 + u] = cstX;  // final c (batch X)
    out[16777216u + (size_t)bY * 256 + u] = hlY;           // final h (batch Y)
    out[16777216u + 8192u + (size_t)bY * 256 + u] = cstY;  // final c (batch Y)
  }
}

extern "C" void kernel_launch(void* const* d_in, const int* in_sizes, int n_in,
                              void* d_out, int out_size, void* d_ws, size_t ws_size,
                              hipStream_t stream) {
  const float* x = (const float*)d_in[0];
  const float* emb = (const float*)d_in[1];
  const float* W_ih = (const float*)d_in[2];
  const float* W_hh = (const float*)d_in[3];
  const float* bias = (const float*)d_in[4];
  float* out = (float*)d_out;
  char* ws = (char*)d_ws;

  unsigned short* zx = (unsigned short*)ws;
  uint4* wpk = (uint4*)(ws + WPK_OFF);

  size_t need = (size_t)WPK_OFF + 262144u;
  if (ws_size < need) {
    fprintf(stderr, "kernel_launch: ws too small: %zu < %zu\n", ws_size, need);
  }

  pack_kernel<<<dim3(16), dim3(1024), 0, stream>>>(W_hh, wpk);
  zx_kernel<<<dim3(1024), dim3(256), 0, stream>>>(x, emb, W_ih, bias, zx);
  lstm_kernel<<<dim3(16), dim3(1024), 0, stream>>>(zx, (const v4i*)wpk, out);
}

// Round 9
// 1611.010 us; speedup vs baseline: 1.8488x; 1.8488x over previous
//
#include <hip/hip_runtime.h>
#include <hip/hip_fp16.h>
#include <cstdio>

// EmbeddingCellLSTM: B=32, S=2048, IN=64, EMB=32, H=256, 4H=1024
//  k1 pack_kernel : W_hh fp32 -> i8 (scale 2032) 16B B-fragments, INTERLEAVED rows:
//                   tile (tr,kc): col m -> W row (m&3)*256 + w*16 + tr*4 + (m>>2)
//                   (4 units x 4 gates per 16-col tile) so gate gather is quad-local.
//  k2 zx_kernel   : zx = (concat(x,emb) @ W_ih^T + b) fp16; block = 64-row stripe, stages x once.
//  k3 lstm_kernel : 32 blocks (1/batch) x 16 waves, transposed MFMA acc[t]=mfma(h_bcast, wf, 0).
//                   Lane (q,n): select acc[q][0] (3 cndmask) = z[gate n&3][unit w*16+q*4+(n>>2)],
//                   ONE activation, gather i,f,g,o via 4x v_mov_dpp quad_perm broadcasts (was 4x
//                   ds_bpermute ~60+cyc LDS round trip), c/h update (quad-replicated), n&3==0
//                   writes i8 h + fp32 out. Barrier = manual "s_waitcnt lgkmcnt(0); s_barrier"
//                   -- __syncthreads drained vmcnt(0) too, stalling every step ~200-500 cyc on
//                   the out-store ack. 2x unrolled (compile-time buffer alternation), distance-2
//                   zx prefetch (OOB-safe into wpk), wave-prio stagger 3,2,1,0 on MFMA cluster.
//  Measured floor: matrix pipe = 64 MFMA-inst/SIMD/step x 16 cyc = 1024 cyc/step (r4-r8, 5x).
//  r7 step = 1695 cyc = 1024 + ~670 exposure; r8 (2 batches/CU) refuted: floor scales with
//  batches/CU (2048+tail measured). This round removes store-drain + bpermute latency from tail.

#define WPK_OFF (134217728u)   // zx = 32*2048*1024*2 bytes, then wpk 256 KB

typedef int v4i __attribute__((ext_vector_type(4)));

static __device__ __forceinline__ unsigned short f16bits(float v) {
  _Float16 h = (_Float16)v;
  return __builtin_bit_cast(unsigned short, h);
}

static __device__ __forceinline__ float h2f(unsigned short b) {
  return (float)__builtin_bit_cast(_Float16, b);
}

// quad_perm broadcast of lane g (0..3) within each aligned 4-lane quad
#define QBCAST(x, g) __builtin_amdgcn_mov_dpp((x), (g) * 0x55, 0xF, 0xF, false)

// ---------------- k1: pack W_hh -> i8 MFMA B-fragments (interleaved unit/gate cols) ----------------
// tile = tr*4+kc ; thread t -> w=t>>6, lane: m=lane&15 (col), q=lane>>4 (K-group)
// col m -> W row (m&3)*256 + w*16 + tr*4 + (m>>2)  [gate m&3, unit w*16+tr*4+(m>>2)]
// frag byte j = W[row][kc*64 + q*16 + j] ; wq = rint(w*2032), |w|<1/16 -> |wq|<=127
__global__ __launch_bounds__(1024) void pack_kernel(const float* __restrict__ Whh,
                                                    uint4* __restrict__ wpk) {
  int tile = blockIdx.x;            // 0..15
  int tr = tile >> 2, kc = tile & 3;
  int t = threadIdx.x;
  int w = t >> 6, lane = t & 63, m = lane & 15, q = lane >> 4;
  int row = (m & 3) * 256 + w * 16 + tr * 4 + (m >> 2);
  const float* src = Whh + row * 256 + kc * 64 + q * 16;
  unsigned int pk[4];
#pragma unroll
  for (int d = 0; d < 4; d++) {
    unsigned int v = 0;
#pragma unroll
    for (int e = 0; e < 4; e++) {
      int qv = (int)rintf(src[d * 4 + e] * 2032.0f);
      v |= ((unsigned int)(qv & 255)) << (8 * e);
    }
    pk[d] = v;
  }
  uint4 o; o.x = pk[0]; o.y = pk[1]; o.z = pk[2]; o.w = pk[3];
  wpk[tile * 1024 + t] = o;
}

// ---------------- k2: zx = concat(x,emb) @ W_ih^T + b (fp16, natural row order) ----------------
// One block per 64-row stripe; x/emb staged once, 16 column tiles looped in-block.
__global__ __launch_bounds__(256) void zx_kernel(const float* __restrict__ x,
                                                 const float* __restrict__ emb,
                                                 const float* __restrict__ Wih,
                                                 const float* __restrict__ bias,
                                                 unsigned short* __restrict__ zx) {
  __shared__ __align__(16) float XeT[96][68];
  __shared__ __align__(16) float WT[96][68];
  int mt = blockIdx.x;              // 0..1023
  int m0 = mt * 64;
  int tid = threadIdx.x;
  for (int idx = tid; idx < 6144; idx += 256) {
    int r = idx / 96, k = idx - r * 96;
    size_t m = (size_t)(m0 + r);
    float v = (k < 64) ? x[m * 64 + k] : emb[m * 32 + (k - 64)];
    XeT[k][r] = v;
  }
  int ty = tid >> 4, tx = tid & 15;
  int r0 = ty * 4, c0 = tx * 4;
  for (int nt = 0; nt < 16; nt++) {
    int n0 = nt * 64;
    __syncthreads();                // protect WT vs previous iter's readers (covers XeT stage on iter 0)
    for (int idx = tid; idx < 6144; idx += 256) {
      int c = idx / 96, k = idx - c * 96;
      WT[k][c] = Wih[(size_t)(n0 + c) * 96 + k];
    }
    __syncthreads();
    float acc[4][4] = {};
    for (int k = 0; k < 96; k++) {
      float4 a = *(const float4*)&XeT[k][r0];
      float4 wv4 = *(const float4*)&WT[k][c0];
      float av[4] = {a.x, a.y, a.z, a.w};
      float wv[4] = {wv4.x, wv4.y, wv4.z, wv4.w};
#pragma unroll
      for (int i = 0; i < 4; i++)
#pragma unroll
        for (int jj = 0; jj < 4; jj++) acc[i][jj] += av[i] * wv[jj];
    }
#pragma unroll
    for (int i = 0; i < 4; i++) {
      size_t m = (size_t)(m0 + r0 + i);
#pragma unroll
      for (int jj = 0; jj < 4; jj++) {
        int col = n0 + c0 + jj;
        zx[m * 1024 + (size_t)col] = f16bits(acc[i][jj] + bias[col]);
      }
    }
  }
}

// ---------------- k3: persistent per-batch LSTM (transposed i8 MFMA, dpp gather) ----------------
__global__ __launch_bounds__(1024, 4) void lstm_kernel(const unsigned short* __restrict__ zx,
                                                       const v4i* __restrict__ wpk,
                                                       float* __restrict__ out) {
  __shared__ __align__(16) char hq[2][256];
  const int t = threadIdx.x, b = blockIdx.x;
  const int w = t >> 6, lane = t & 63, q = lane >> 4, n = lane & 15;

  // full W_hh residency: 16 frags x 16B i8 = 64 regs (B-operand; AGPR-friendly)
  v4i wf[16];
#pragma unroll
  for (int i = 0; i < 16; i++) wf[i] = wpk[i * 1024 + t];

  if (t < 128) ((unsigned int*)hq)[t] = 0;   // zero both h buffers (2x256 i8)
  __syncthreads();

  // static stagger prio for the MFMA phase (robust to either wave->SIMD map)
  const int pr = 3 - (((w >> 2) ^ w) & 3);

  const float dq = 1.0f / (2032.0f * 127.0f);
  const int g = n & 3;                            // this lane's gate
  const int u = w * 16 + q * 4 + (n >> 2);        // this lane's unit
  const bool isg = (g == 2);                      // gate 2 is tanh
  const float sc = isg ? 2.88539008f : 1.44269504f;
  const unsigned short* zp = zx + (size_t)b * (2048u * 1024u) + (unsigned)(g * 256 + u);
  const bool wr = (g == 0);                       // quad lane 0 writes
  float* op = out + (size_t)b * (2048u * 256u) + u;
  char* hw0 = &hq[1][u];                          // written in even steps (for s+1)
  char* hw1 = &hq[0][u];                          // written in odd steps
  const v4i zerov = {0, 0, 0, 0};                 // persistent MFMA C operand (D != C)

  float cst = 0.f, hlast = 0.f;
  unsigned short za = zp[0];                      // zx for even step s
  unsigned short zb = zp[1024];                   // zx for odd step s+1

#define LSTM_STEP(HC, HWPTR, ZREG, SIDX)                                              \
  {                                                                                   \
    const char* hc = (HC);                                                            \
    v4i bq[4];                                                                        \
    _Pragma("unroll")                                                                 \
    for (int c = 0; c < 4; c++) bq[c] = *(const v4i*)(hc + c * 64 + q * 16);          \
    unsigned short zu = ZREG;                                                         \
    ZREG = zp[(size_t)((SIDX) + 2) << 10];  /* distance-2 prefetch; tail OOB-safe */  \
    if (pr == 3) __builtin_amdgcn_s_setprio(3);                                       \
    else if (pr == 2) __builtin_amdgcn_s_setprio(2);                                  \
    else if (pr == 1) __builtin_amdgcn_s_setprio(1);                                  \
    v4i acc[4];                                                                       \
    _Pragma("unroll")                                                                 \
    for (int tt = 0; tt < 4; tt++)                                                    \
      acc[tt] = __builtin_amdgcn_mfma_i32_16x16x64_i8(bq[0], wf[tt * 4 + 0], zerov, 0, 0, 0); \
    _Pragma("unroll")                                                                 \
    for (int c = 1; c < 4; c++)                                                       \
      _Pragma("unroll")                                                               \
      for (int tt = 0; tt < 4; tt++)                                                  \
        acc[tt] = __builtin_amdgcn_mfma_i32_16x16x64_i8(bq[c], wf[tt * 4 + c], acc[tt], 0, 0, 0); \
    __builtin_amdgcn_s_setprio(0);                                                    \
    int tlo = (q & 1) ? acc[1][0] : acc[0][0];                                        \
    int thi = (q & 1) ? acc[3][0] : acc[2][0];                                        \
    int zi  = (q & 2) ? thi : tlo;                                                    \
    float z = (float)zi * dq + h2f(zu);                                               \
    float e = __builtin_amdgcn_exp2f(-sc * z);                                        \
    float r = __builtin_amdgcn_rcpf(1.f + e);                                         \
    float a = isg ? (2.f * r - 1.f) : r;                                              \
    int ab = __builtin_bit_cast(int, a);                                              \
    float ai = __builtin_bit_cast(float, QBCAST(ab, 0));                              \
    float af = __builtin_bit_cast(float, QBCAST(ab, 1));                              \
    float ag = __builtin_bit_cast(float, QBCAST(ab, 2));                              \
    float ao = __builtin_bit_cast(float, QBCAST(ab, 3));                              \
    float cn = af * cst + ai * ag;                                                    \
    float e2 = __builtin_amdgcn_exp2f(-2.88539008f * cn);                             \
    float th = 2.f * __builtin_amdgcn_rcpf(1.f + e2) - 1.f;                           \
    float h = ao * th;                                                                \
    cst = cn;                                                                         \
    hlast = h;                                                                        \
    if (wr) {                                                                         \
      *(HWPTR) = (char)(int)rintf(h * 127.0f);                                        \
      op[(size_t)(SIDX) * 256] = h;                                                   \
    }                                                                                 \
    asm volatile("s_waitcnt lgkmcnt(0)\n\ts_barrier" ::: "memory");                   \
  }

  for (int s = 0; s < 2048; s += 2) {
    LSTM_STEP(hq[0], hw0, za, s)       // even: read buf0, write buf1
    LSTM_STEP(hq[1], hw1, zb, s + 1)   // odd : read buf1, write buf0
  }
#undef LSTM_STEP

  if (wr) {
    out[16777216u + (size_t)b * 256 + u] = hlast;          // final h
    out[16777216u + 8192u + (size_t)b * 256 + u] = cst;    // final c
  }
}

extern "C" void kernel_launch(void* const* d_in, const int* in_sizes, int n_in,
                              void* d_out, int out_size, void* d_ws, size_t ws_size,
                              hipStream_t stream) {
  const float* x = (const float*)d_in[0];
  const float* emb = (const float*)d_in[1];
  const float* W_ih = (const float*)d_in[2];
  const float* W_hh = (const float*)d_in[3];
  const float* bias = (const float*)d_in[4];
  float* out = (float*)d_out;
  char* ws = (char*)d_ws;

  unsigned short* zx = (unsigned short*)ws;
  uint4* wpk = (uint4*)(ws + WPK_OFF);

  size_t need = (size_t)WPK_OFF + 262144u;
  if (ws_size < need) {
    fprintf(stderr, "kernel_launch: ws too small: %zu < %zu\n", ws_size, need);
  }

  pack_kernel<<<dim3(16), dim3(1024), 0, stream>>>(W_hh, wpk);
  zx_kernel<<<dim3(1024), dim3(256), 0, stream>>>(x, emb, W_ih, bias, zx);
  lstm_kernel<<<dim3(32), dim3(1024), 0, stream>>>(zx, (const v4i*)wpk, out);
}

// Round 10
// 1517.106 us; speedup vs baseline: 1.9633x; 1.0619x over previous
//
#include <hip/hip_runtime.h>
#include <hip/hip_fp16.h>
#include <cstdio>

// EmbeddingCellLSTM: B=32, S=2048, IN=64, EMB=32, H=256, 4H=1024
//  k1 pack_kernel : W_hh fp32 -> i8 (scale 2032) 16B B-fragments, interleaved unit/gate cols.
//  k2 zx_kernel   : zx = (concat(x,emb) @ W_ih^T + b) fp16 via mfma_f32_16x16x32_f16
//                   (inputs cast fp16, f32 accum; adds ~2.4e-4 zx noise, negligible vs 1.3e-3
//                   h-quant). Was f32 VALU GEMM at its 82us vector-pipe floor (~150us real);
//                   MFMA makes it staging-bound ~40us. Block = 64-row stripe, Xe staged once,
//                   16 col-tiles looped; Wih re-read per block is L2-resident (384 KB).
//  k3 lstm_kernel : r9 structure (transposed MFMA, dpp quad gather, lean barrier) + r10 trims:
//                   zx prefetch hoisted above LDS bq reads; magic-rounding h quant (fma+sub).
//  Locked-in facts: matrix busy = 1024 cyc/step (r4-r9, 6x) = i8 DENSE PEAK (1018 MAC/cyc/SIMD)
//  -> MFMA floor immovable (MX-fp8 is SLOWER: 948 MAC/cyc); MFMA C-chain is issue-limited so
//  chain-splitting is useless; exposed tail ~577 cyc = last-wave dependent chain + barrier +
//  LDS turnaround, trimmable only marginally.

#define WPK_OFF (134217728u)   // zx = 32*2048*1024*2 bytes, then wpk 256 KB

typedef int v4i __attribute__((ext_vector_type(4)));
typedef _Float16 v8h __attribute__((ext_vector_type(8)));
typedef float f32x4 __attribute__((ext_vector_type(4)));

static __device__ __forceinline__ unsigned short f16bits(float v) {
  _Float16 h = (_Float16)v;
  return __builtin_bit_cast(unsigned short, h);
}

static __device__ __forceinline__ float h2f(unsigned short b) {
  return (float)__builtin_bit_cast(_Float16, b);
}

// quad_perm broadcast of lane g (0..3) within each aligned 4-lane quad
#define QBCAST(x, g) __builtin_amdgcn_mov_dpp((x), (g) * 0x55, 0xF, 0xF, false)

// ---------------- k1: pack W_hh -> i8 MFMA B-fragments (interleaved unit/gate cols) ----------------
// tile = tr*4+kc ; thread t -> w=t>>6, lane: m=lane&15 (col), q=lane>>4 (K-group)
// col m -> W row (m&3)*256 + w*16 + tr*4 + (m>>2)  [gate m&3, unit w*16+tr*4+(m>>2)]
// frag byte j = W[row][kc*64 + q*16 + j] ; wq = rint(w*2032), |w|<1/16 -> |wq|<=127
__global__ __launch_bounds__(1024) void pack_kernel(const float* __restrict__ Whh,
                                                    uint4* __restrict__ wpk) {
  int tile = blockIdx.x;            // 0..15
  int tr = tile >> 2, kc = tile & 3;
  int t = threadIdx.x;
  int w = t >> 6, lane = t & 63, m = lane & 15, q = lane >> 4;
  int row = (m & 3) * 256 + w * 16 + tr * 4 + (m >> 2);
  const float* src = Whh + row * 256 + kc * 64 + q * 16;
  unsigned int pk[4];
#pragma unroll
  for (int d = 0; d < 4; d++) {
    unsigned int v = 0;
#pragma unroll
    for (int e = 0; e < 4; e++) {
      int qv = (int)rintf(src[d * 4 + e] * 2032.0f);
      v |= ((unsigned int)(qv & 255)) << (8 * e);
    }
    pk[d] = v;
  }
  uint4 o; o.x = pk[0]; o.y = pk[1]; o.z = pk[2]; o.w = pk[3];
  wpk[tile * 1024 + t] = o;
}

// ---------------- k2: zx = concat(x,emb) @ W_ih^T + b via f16 MFMA (f32 accum) ----------------
// Block = 64-row stripe (1024 blocks), 256 thr (4 waves). XeT[64][100] fp16 staged once;
// WT[64][100] fp16 per col-tile (L2-resident source). Wave ww: rows ww*16..+15, all 4 n-subtiles,
// K=96 as 3 chunks of 32. A row = lane&15, k-group = lane>>4 (8 f16 = 16B). [100] pad: row
// stride 50 dwords, 50%32=18 -> 16 rows hit 16 distinct banks (conflict-free).
__global__ __launch_bounds__(256) void zx_kernel(const float* __restrict__ x,
                                                 const float* __restrict__ emb,
                                                 const float* __restrict__ Wih,
                                                 const float* __restrict__ bias,
                                                 unsigned short* __restrict__ zx) {
  __shared__ __align__(16) _Float16 XeT[64][100];
  __shared__ __align__(16) _Float16 WT[64][100];
  int mt = blockIdx.x;              // 0..1023
  int m0 = mt * 64;
  int tid = threadIdx.x;
  for (int idx = tid; idx < 6144; idx += 256) {
    int r = idx / 96, k = idx - r * 96;
    size_t m = (size_t)(m0 + r);
    float v = (k < 64) ? x[m * 64 + k] : emb[m * 32 + (k - 64)];
    XeT[r][k] = (_Float16)v;
  }
  __syncthreads();

  int ww = tid >> 6, lane = tid & 63, qq = lane >> 4, nl = lane & 15;
  // A-frags: fixed per block (Xe rows of this wave), hoisted out of the nt loop
  v8h af[3];
#pragma unroll
  for (int kc = 0; kc < 3; kc++)
    af[kc] = *(const v8h*)&XeT[ww * 16 + nl][kc * 32 + qq * 8];

  for (int nt = 0; nt < 16; nt++) {
    int n0 = nt * 64;
    __syncthreads();                // protect WT vs previous iter's readers
    for (int idx = tid; idx < 6144; idx += 256) {
      int c = idx / 96, k = idx - c * 96;
      WT[c][k] = (_Float16)Wih[(size_t)(n0 + c) * 96 + k];
    }
    __syncthreads();
#pragma unroll
    for (int nn = 0; nn < 4; nn++) {
      f32x4 acc = {0.f, 0.f, 0.f, 0.f};
#pragma unroll
      for (int kc = 0; kc < 3; kc++) {
        v8h bf = *(const v8h*)&WT[nn * 16 + nl][kc * 32 + qq * 8];
        acc = __builtin_amdgcn_mfma_f32_16x16x32_f16(af[kc], bf, acc, 0, 0, 0);
      }
      int col = n0 + nn * 16 + nl;
      float bv = bias[col];
#pragma unroll
      for (int r = 0; r < 4; r++) {
        size_t m = (size_t)(m0 + ww * 16 + qq * 4 + r);
        zx[m * 1024 + (size_t)col] = f16bits(acc[r] + bv);
      }
    }
  }
}

// ---------------- k3: persistent per-batch LSTM (transposed i8 MFMA, dpp gather) ----------------
__global__ __launch_bounds__(1024, 4) void lstm_kernel(const unsigned short* __restrict__ zx,
                                                       const v4i* __restrict__ wpk,
                                                       float* __restrict__ out) {
  __shared__ __align__(16) char hq[2][256];
  const int t = threadIdx.x, b = blockIdx.x;
  const int w = t >> 6, lane = t & 63, q = lane >> 4, n = lane & 15;

  // full W_hh residency: 16 frags x 16B i8 = 64 regs (B-operand; AGPR-friendly)
  v4i wf[16];
#pragma unroll
  for (int i = 0; i < 16; i++) wf[i] = wpk[i * 1024 + t];

  if (t < 128) ((unsigned int*)hq)[t] = 0;   // zero both h buffers (2x256 i8)
  __syncthreads();

  // static stagger prio for the MFMA phase (robust to either wave->SIMD map)
  const int pr = 3 - (((w >> 2) ^ w) & 3);

  const float dq = 1.0f / (2032.0f * 127.0f);
  const int g = n & 3;                            // this lane's gate
  const int u = w * 16 + q * 4 + (n >> 2);        // this lane's unit
  const bool isg = (g == 2);                      // gate 2 is tanh
  const float sc = isg ? 2.88539008f : 1.44269504f;
  const unsigned short* zp = zx + (size_t)b * (2048u * 1024u) + (unsigned)(g * 256 + u);
  const bool wr = (g == 0);                       // quad lane 0 writes
  float* op = out + (size_t)b * (2048u * 256u) + u;
  char* hw0 = &hq[1][u];                          // written in even steps (for s+1)
  char* hw1 = &hq[0][u];                          // written in odd steps
  const v4i zerov = {0, 0, 0, 0};                 // persistent MFMA C operand (D != C)

  float cst = 0.f, hlast = 0.f;
  unsigned short za = zp[0];                      // zx for even step s
  unsigned short zb = zp[1024];                   // zx for odd step s+1

#define LSTM_STEP(HC, HWPTR, ZREG, SIDX)                                              \
  {                                                                                   \
    unsigned short zu = ZREG;                                                         \
    ZREG = zp[(size_t)((SIDX) + 2) << 10];  /* global prefetch FIRST (indep of LDS) */\
    const char* hc = (HC);                                                            \
    v4i bq[4];                                                                        \
    _Pragma("unroll")                                                                 \
    for (int c = 0; c < 4; c++) bq[c] = *(const v4i*)(hc + c * 64 + q * 16);          \
    if (pr == 3) __builtin_amdgcn_s_setprio(3);                                       \
    else if (pr == 2) __builtin_amdgcn_s_setprio(2);                                  \
    else if (pr == 1) __builtin_amdgcn_s_setprio(1);                                  \
    v4i acc[4];                                                                       \
    _Pragma("unroll")                                                                 \
    for (int tt = 0; tt < 4; tt++)                                                    \
      acc[tt] = __builtin_amdgcn_mfma_i32_16x16x64_i8(bq[0], wf[tt * 4 + 0], zerov, 0, 0, 0); \
    _Pragma("unroll")                                                                 \
    for (int c = 1; c < 4; c++)                                                       \
      _Pragma("unroll")                                                               \
      for (int tt = 0; tt < 4; tt++)                                                  \
        acc[tt] = __builtin_amdgcn_mfma_i32_16x16x64_i8(bq[c], wf[tt * 4 + c], acc[tt], 0, 0, 0); \
    __builtin_amdgcn_s_setprio(0);                                                    \
    int tlo = (q & 1) ? acc[1][0] : acc[0][0];                                        \
    int thi = (q & 1) ? acc[3][0] : acc[2][0];                                        \
    int zi  = (q & 2) ? thi : tlo;                                                    \
    float z = (float)zi * dq + h2f(zu);                                               \
    float e = __builtin_amdgcn_exp2f(-sc * z);                                        \
    float r = __builtin_amdgcn_rcpf(1.f + e);                                         \
    float a = isg ? (2.f * r - 1.f) : r;                                              \
    int ab = __builtin_bit_cast(int, a);                                              \
    float ai = __builtin_bit_cast(float, QBCAST(ab, 0));                              \
    float af = __builtin_bit_cast(float, QBCAST(ab, 1));                              \
    float ag = __builtin_bit_cast(float, QBCAST(ab, 2));                              \
    float ao = __builtin_bit_cast(float, QBCAST(ab, 3));                              \
    float cn = af * cst + ai * ag;                                                    \
    float e2 = __builtin_amdgcn_exp2f(-2.88539008f * cn);                             \
    float th = 2.f * __builtin_amdgcn_rcpf(1.f + e2) - 1.f;                           \
    float h = ao * th;                                                                \
    cst = cn;                                                                         \
    hlast = h;                                                                        \
    if (wr) {                                                                         \
      /* magic rounding: fma into 1.5*2^23 -> mantissa low bits = rint(h*127) */      \
      float fr = __builtin_fmaf(h, 127.0f, 12582912.0f);                              \
      int iq = __builtin_bit_cast(int, fr) - 0x4B400000;                              \
      *(HWPTR) = (char)iq;                                                            \
      op[(size_t)(SIDX) * 256] = h;                                                   \
    }                                                                                 \
    asm volatile("s_waitcnt lgkmcnt(0)\n\ts_barrier" ::: "memory");                   \
  }

  for (int s = 0; s < 2048; s += 2) {
    LSTM_STEP(hq[0], hw0, za, s)       // even: read buf0, write buf1
    LSTM_STEP(hq[1], hw1, zb, s + 1)   // odd : read buf1, write buf0
  }
#undef LSTM_STEP

  if (wr) {
    out[16777216u + (size_t)b * 256 + u] = hlast;          // final h
    out[16777216u + 8192u + (size_t)b * 256 + u] = cst;    // final c
  }
}

extern "C" void kernel_launch(void* const* d_in, const int* in_sizes, int n_in,
                              void* d_out, int out_size, void* d_ws, size_t ws_size,
                              hipStream_t stream) {
  const float* x = (const float*)d_in[0];
  const float* emb = (const float*)d_in[1];
  const float* W_ih = (const float*)d_in[2];
  const float* W_hh = (const float*)d_in[3];
  const float* bias = (const float*)d_in[4];
  float* out = (float*)d_out;
  char* ws = (char*)d_ws;

  unsigned short* zx = (unsigned short*)ws;
  uint4* wpk = (uint4*)(ws + WPK_OFF);

  size_t need = (size_t)WPK_OFF + 262144u;
  if (ws_size < need) {
    fprintf(stderr, "kernel_launch: ws too small: %zu < %zu\n", ws_size, need);
  }

  pack_kernel<<<dim3(16), dim3(1024), 0, stream>>>(W_hh, wpk);
  zx_kernel<<<dim3(1024), dim3(256), 0, stream>>>(x, emb, W_ih, bias, zx);
  lstm_kernel<<<dim3(32), dim3(1024), 0, stream>>>(zx, (const v4i*)wpk, out);
}